// Round 10
// baseline (3987.057 us; speedup 1.0000x reference)
//
#include <hip/hip_runtime.h>

// Problem constants
#define Nb   256
#define Tt   2048
#define INs  6
#define HID  128
#define STs  64
#define LAY  134
#define OUTs 6
#define VDW  72      // packed dwords per activation vector (144 f16 slots, zero-pad 134..143)
#define HB_ODD 72    // f16 slot base of the odd K-half

typedef __fp16 f16x2 __attribute__((ext_vector_type(2)));
typedef __fp16 f16x8 __attribute__((ext_vector_type(8)));

__device__ __forceinline__ float exp2_fast(float x) {
#if __has_builtin(__builtin_amdgcn_exp2f)
    return __builtin_amdgcn_exp2f(x);
#else
    return exp2f(x);
#endif
}
__device__ __forceinline__ float rcp_fast(float x) {
#if __has_builtin(__builtin_amdgcn_rcpf)
    return __builtin_amdgcn_rcpf(x);
#else
    return 1.0f / x;
#endif
}
__device__ __forceinline__ float tanh_fast(float x) {
    float e = exp2_fast(x * 2.8853900817779268f);
    return 1.0f - 2.0f * rcp_fast(e + 1.0f);
}
__device__ __forceinline__ unsigned pack2(float a, float b) {
#if __has_builtin(__builtin_amdgcn_cvt_pkrtz)
    union { f16x2 h; unsigned u; } u;
    u.h = __builtin_amdgcn_cvt_pkrtz(a, b);
    return u.u;
#else
    union { f16x2 h; unsigned u; } u;
    u.h[0] = (__fp16)a; u.h[1] = (__fp16)b;
    return u.u;
#endif
}
__device__ __forceinline__ unsigned pack2w(float a, float b) {   // RNE for weights
    union { f16x2 h; unsigned u; } u;
    u.h[0] = (__fp16)a; u.h[1] = (__fp16)b;
    return u.u;
}
__device__ __forceinline__ float dot2p(unsigned av, f16x2 wv, float c) {
    union { unsigned u; f16x2 f; } ua; ua.u = av;
#if __has_builtin(__builtin_amdgcn_fdot2)
    return __builtin_amdgcn_fdot2(ua.f, wv, c, false);
#else
    return c + (float)ua.f[0] * (float)wv[0] + (float)ua.f[1] * (float)wv[1];
#endif
}
__device__ __forceinline__ float dotdw(unsigned av, unsigned wv, float c) {
    union { unsigned u; f16x2 f; } uw; uw.u = wv;
    return dot2p(av, uw.f, c);
}

// ---- 9 named f16x8 regs per weight set (36 dwords = one K-half of a column) ----
#define DECLW(P) f16x8 P##0={},P##1={},P##2={},P##3={},P##4={},P##5={},P##6={},P##7={},P##8={}

#define LOADW1(P,k,Wsrc,od,colv,hbv) { f16x8 tmp; \
    _Pragma("unroll") for (int q=0;q<8;++q){ int r=(hbv)+8*(k)+q; \
        float f=(r<LAY)?(Wsrc)[r*(od)+(colv)]:0.f; tmp[q]=(__fp16)f; } P##k=tmp; }
#define LOADSET(P,Wsrc,od,colv,hbv) \
    LOADW1(P,0,Wsrc,od,colv,hbv) LOADW1(P,1,Wsrc,od,colv,hbv) LOADW1(P,2,Wsrc,od,colv,hbv) \
    LOADW1(P,3,Wsrc,od,colv,hbv) LOADW1(P,4,Wsrc,od,colv,hbv) LOADW1(P,5,Wsrc,od,colv,hbv) \
    LOADW1(P,6,Wsrc,od,colv,hbv) LOADW1(P,7,Wsrc,od,colv,hbv) LOADW1(P,8,Wsrc,od,colv,hbv)

#define DOTK(P,k) { \
    a0=dot2p(x##k.x,__builtin_shufflevector(P##k,P##k,0,1),a0); \
    a1=dot2p(x##k.y,__builtin_shufflevector(P##k,P##k,2,3),a1); \
    a2=dot2p(x##k.z,__builtin_shufflevector(P##k,P##k,4,5),a2); \
    a3=dot2p(x##k.w,__builtin_shufflevector(P##k,P##k,6,7),a3); }
#define DOTSET(P) DOTK(P,0) DOTK(P,1) DOTK(P,2) DOTK(P,3) DOTK(P,4) DOTK(P,5) DOTK(P,6) DOTK(P,7) DOTK(P,8)

#define LOADX(buf) const uint4* a4_=(const uint4*)(buf)+hoff9; \
    uint4 x0=a4_[0],x1=a4_[1],x2=a4_[2],x3=a4_[3],x4=a4_[4],x5=a4_[5],x6=a4_[6],x7=a4_[7],x8=a4_[8]

#define OVK(k) { uint4 wv=w4_[k]; o0=dotdw(x##k.x,wv.x,o0); o1=dotdw(x##k.y,wv.y,o1); \
                 o2=dotdw(x##k.z,wv.z,o2); o3=dotdw(x##k.w,wv.w,o3); }
#define OVSET OVK(0) OVK(1) OVK(2) OVK(3) OVK(4) OVK(5) OVK(6) OVK(7) OVK(8)

// 512 threads. Thread bits: half=tid&1 (K-half), mat=(tid>>1)&1 (Wg1/Wg2 or Wa/Wb),
// col=tid>>2 (0..127). All threads active in all 3 phases (K-split pairs, DPP combine).
// Overhang cols 128..133: LDS-streamed by threads 0..23 (P1) / 488..511 (P2), reusing
// their activation registers. H: 32-step LDS ring, projected+stored every 32 steps.
__global__ __launch_bounds__(512, 1) __attribute__((amdgpu_waves_per_eu(2, 2)))
void lmsc_kernel(const float* __restrict__ X,  const float* __restrict__ H0,
                 const float* __restrict__ Wg1, const float* __restrict__ bg1,
                 const float* __restrict__ Wg2, const float* __restrict__ bg2,
                 const float* __restrict__ Wa,  const float* __restrict__ ba,
                 const float* __restrict__ Wb,  const float* __restrict__ bb,
                 const float* __restrict__ Wh,  const float* __restrict__ bh,
                 const float* __restrict__ Wo,  const float* __restrict__ bo,
                 float* __restrict__ out)
{
    __shared__ float Xls[Tt * INs];                     // 48 KB
    __shared__ alignas(16) float Hhist[32][HID];        // 16 KB H ring
    __shared__ alignas(16) float WolT[OUTs][HID];       // 3 KB transposed Wo
    __shared__ float H0l[STs];
    __shared__ float bol[OUTs];
    __shared__ alignas(16) unsigned OvW1[12][VDW];      // overhang cols, layer 0
    __shared__ alignas(16) unsigned OvW2[12][VDW];      // overhang cols, layer 1
    __shared__ alignas(16) unsigned LvX[VDW];
    __shared__ alignas(16) unsigned LvB[VDW];
    __shared__ alignas(16) unsigned LvC[VDW];
    __shared__ float nrm[2];

    const int tid  = threadIdx.x;
    const int n    = blockIdx.x;
    const int half = tid & 1;
    const int mat  = (tid >> 1) & 1;
    const int col  = tid >> 2;
    const int hoff9 = half * 9;
    const int hb    = half * HB_ODD;
    __fp16* LvX16 = (__fp16*)LvX;
    __fp16* LvB16 = (__fp16*)LvB;
    __fp16* LvC16 = (__fp16*)LvC;

    // ---------------- staging ----------------
    {
        const float4* Xg  = (const float4*)(X + (size_t)n * (Tt * INs));
        float4*       Xl4 = (float4*)Xls;
        for (int i = tid; i < (Tt * INs) / 4; i += 512) Xl4[i] = Xg[i];
    }
    if (tid < STs) H0l[tid] = H0[n * STs + tid];
    for (int i = tid; i < OUTs * HID; i += 512) {
        int o = i >> 7, l2 = i & 127;
        WolT[o][l2] = Wo[l2 * OUTs + o];
    }
    if (tid < OUTs) bol[tid] = bo[tid];
    if (tid < 5) LvX[67 + tid] = 0u;
    else if (tid < 10) LvB[62 + tid] = 0u;
    else if (tid < 15) LvC[57 + tid] = 0u;
    // overhang weight columns -> LDS (packed f16x2, slot == row)
    if (tid >= 64 && tid < 88) {
        int i = tid - 64; int L = (i >= 12); int d = i - L * 12;     // d 0..11
        int c = 128 + (d >> 1); int m = d & 1;
        const float* src = (m ? Wg2 : Wg1) + L * LAY * LAY;
        unsigned* dst = L ? OvW2[d] : OvW1[d];
        for (int q = 0; q < VDW; ++q) {
            int r0 = 2 * q, r1 = 2 * q + 1;
            float f0 = (r0 < LAY) ? src[r0 * LAY + c] : 0.f;
            float f1 = (r1 < LAY) ? src[r1 * LAY + c] : 0.f;
            dst[q] = pack2w(f0, f1);
        }
    }

    // ------- per-thread weights (108 dwords): gate L0, gate L1, alpha/beta -------
    DECLW(u); DECLW(v); DECLW(p);
    const float* Wgm = mat ? Wg2 : Wg1;
    LOADSET(u, Wgm, LAY, col, hb);
    LOADSET(v, Wgm + LAY * LAY, LAY, col, hb);
    const float* Wab = mat ? Wb : Wa;
    LOADSET(p, Wab, HID, col, hb);
    float gb0 = (mat ? bg2 : bg1)[col];
    float gb1 = (mat ? bg2 : bg1)[LAY + col];
    float pb  = (mat ? bb : ba)[col];
    float ovb = 0.f;
    if (tid < 24)        ovb = (((tid >> 1) & 1) ? bg2 : bg1)[128 + (tid >> 2)];
    else if (tid >= 488) { int e = tid - 488; ovb = (((e >> 1) & 1) ? bg2 : bg1)[LAY + 128 + (e >> 2)]; }

    __syncthreads();

    // ---------------- init: S0 = H0 @ Wh + bh ; norm_0 ; x-part ----------------
    float h = 0.f;
    if ((tid & 3) == 0) {
        float s = bh[col];
        for (int k = 0; k < STs; ++k) s += H0l[k] * Wh[k * HID + col];
        h = s;
        LvX16[6 + col] = (__fp16)s;
    }
    if (tid == 56) {
        float s = 0.f;
#pragma unroll
        for (int i = 0; i < 6; ++i) s += Xls[i] * Xls[i];
        float nv = sqrtf(s), rn = rcp_fast(nv);
        nrm[0] = nv;
        LvX[0] = pack2(Xls[0]*rn, Xls[1]*rn);
        LvX[1] = pack2(Xls[2]*rn, Xls[3]*rn);
        LvX[2] = pack2(Xls[4]*rn, Xls[5]*rn);
    }
    __syncthreads();

    const float LOG2E = 1.4426950408889634f;

#pragma unroll 1
    for (int t = 0; t < Tt; ++t) {
        unsigned nx0 = 0, nx1 = 0, nx2 = 0;          // thread 56: packed x for t+1
        // ---- P1: gate layer 1 (all threads, K-split) ----
        {
            LOADX(LvX);
            float a0 = 0.f, a1 = 0.f, a2 = 0.f, a3 = 0.f;
            DOTSET(u);
            float s = (a0 + a1) + (a2 + a3);
            s += __shfl_xor(s, 1, 64);               // combine K-halves (DPP)
            s += gb0;
            float tn = tanh_fast(s);
            float to = __shfl_xor(tn, 2, 64);        // cross-matrix (DPP)
            if ((tid & 3) == 0) LvB16[col] = (__fp16)(tn * to);
            if (tid < 24) {                          // overhang, reuses x0..x8
                const uint4* w4_ = (const uint4*)OvW1[tid >> 1] + hoff9;
                float o0 = 0.f, o1 = 0.f, o2 = 0.f, o3 = 0.f;
                OVSET;
                float so = (o0 + o1) + (o2 + o3);
                so += __shfl_xor(so, 1, 64);
                so += ovb;
                float tno = tanh_fast(so);
                float too = __shfl_xor(tno, 2, 64);
                if ((tid & 3) == 0) LvB16[128 + (tid >> 2)] = (__fp16)(tno * too);
            } else if (tid == 56 && (t + 1) < Tt) {  // next-step norm + x-pack
                const float* xp = &Xls[(t + 1) * INs];
                float s2 = 0.f;
#pragma unroll
                for (int i = 0; i < 6; ++i) s2 += xp[i] * xp[i];
                float nv = sqrtf(s2), rn = rcp_fast(nv);
                nrm[(t + 1) & 1] = nv;
                nx0 = pack2(xp[0]*rn, xp[1]*rn);
                nx1 = pack2(xp[2]*rn, xp[3]*rn);
                nx2 = pack2(xp[4]*rn, xp[5]*rn);
            }
        }
        __syncthreads();
        // ---- P2: gate layer 2 ----
        {
            LOADX(LvB);
            float a0 = 0.f, a1 = 0.f, a2 = 0.f, a3 = 0.f;
            DOTSET(v);
            float s = (a0 + a1) + (a2 + a3);
            s += __shfl_xor(s, 1, 64);
            s += gb1;
            float tn = tanh_fast(s);
            float to = __shfl_xor(tn, 2, 64);
            if ((tid & 3) == 0) LvC16[col] = (__fp16)(tn * to);
            if (tid >= 488) {
                int e = tid - 488;
                const uint4* w4_ = (const uint4*)OvW2[e >> 1] + hoff9;
                float o0 = 0.f, o1 = 0.f, o2 = 0.f, o3 = 0.f;
                OVSET;
                float so = (o0 + o1) + (o2 + o3);
                so += __shfl_xor(so, 1, 64);
                so += ovb;
                float tno = tanh_fast(so);
                float too = __shfl_xor(tno, 2, 64);
                if ((e & 3) == 0) LvC16[128 + (e >> 2)] = (__fp16)(tno * too);
            } else if (tid == 56 && (t + 1) < Tt) {
                LvX[0] = nx0; LvX[1] = nx1; LvX[2] = nx2;
            }
        }
        __syncthreads();
        // ---- P3: alpha/beta + H update (fused; beta crosses mats via DPP) ----
        {
            LOADX(LvC);
            float a0 = 0.f, a1 = 0.f, a2 = 0.f, a3 = 0.f;
            DOTSET(p);
            float s = (a0 + a1) + (a2 + a3);
            s += __shfl_xor(s, 1, 64);
            s += pb;
            float tn = tanh_fast(s);                 // beta on mat=1 threads
            float beta = __shfl_xor(tn, 2, 64);
            if ((tid & 3) == 0) {
                float alpha = exp2_fast(s * LOG2E);
                float e2 = exp2_fast(-alpha * nrm[t & 1] * LOG2E);
                h = e2 * (h - beta) + beta;
                Hhist[t & 31][col] = h;
                LvX16[6 + col] = (__fp16)h;
            }
        }
        __syncthreads();
        // ---- flush: project 32 buffered H rows every 32 steps ----
        if ((t & 31) == 31) {
            if (tid < 192) {
                int fs = tid / 6, fo = tid - fs * 6;
                float acc = bol[fo];
                const float4* hr = (const float4*)(&Hhist[fs][0]);
                const float4* wr = (const float4*)(&WolT[fo][0]);
#pragma unroll
                for (int k2 = 0; k2 < HID / 4; ++k2) {
                    float4 hv = hr[k2], wv = wr[k2];
                    acc += hv.x*wv.x + hv.y*wv.y + hv.z*wv.z + hv.w*wv.w;
                }
                out[((size_t)n * Tt + (t - 31) + fs) * OUTs + fo] = acc;
            }
            __syncthreads();
        }
    }
}

extern "C" void kernel_launch(void* const* d_in, const int* in_sizes, int n_in,
                              void* d_out, int out_size, void* d_ws, size_t ws_size,
                              hipStream_t stream) {
    const float* X   = (const float*)d_in[0];
    const float* H0  = (const float*)d_in[1];
    const float* Wg1 = (const float*)d_in[2];
    const float* bg1 = (const float*)d_in[3];
    const float* Wg2 = (const float*)d_in[4];
    const float* bg2 = (const float*)d_in[5];
    const float* Wa  = (const float*)d_in[6];
    const float* ba  = (const float*)d_in[7];
    const float* Wb  = (const float*)d_in[8];
    const float* bb  = (const float*)d_in[9];
    const float* Wh  = (const float*)d_in[10];
    const float* bh  = (const float*)d_in[11];
    const float* Wo  = (const float*)d_in[12];
    const float* bo  = (const float*)d_in[13];
    float* out = (float*)d_out;

    hipLaunchKernelGGL(lmsc_kernel, dim3(Nb), dim3(512), 0, stream,
                       X, H0, Wg1, bg1, Wg2, bg2, Wa, ba, Wb, bb, Wh, bh, Wo, bo, out);
}